// Round 1
// baseline (58.263 us; speedup 1.0000x reference)
//
#include <hip/hip_runtime.h>

// GraphUpSample: per-node Linear(3 -> 3*k) over 16 nodes, reshape/transpose,
// then the reference's sequentially-aliased in-place column permutation.
// The aliased loop collapses to a static gather: out col c <- z col SRC[c].

#define BATCH 8192
#define FEAT  64
#define BF_TOTAL (BATCH * FEAT)      // 524288 rows
#define ROWS_PER_BLOCK 64
#define THREADS 256

// Final column -> source column of the pre-permutation tensor z
// (z[b,f,c, n*2+m] = einsum y[b,f,n, c*2+m]); derived by exact simulation
// of the 32 aliased in-place assignments.
__constant__ int c_SRC[32] = {
    0, 2, 4, 6, 8, 10, 12, 14,
    1, 5, 9, 13, 3, 11, 7, 15,
    1, 3, 5, 7, 9, 11, 13, 15,
    3, 7, 11, 15, 7, 15, 15, 31
};

__global__ __launch_bounds__(THREADS)
void GraphUpSample_12120397709982_kernel(const float* __restrict__ x,
                                         const float* __restrict__ W,
                                         const float* __restrict__ bia,
                                         float* __restrict__ out)
{
    // x row = 48 floats ([3][16]); out row = 96 floats ([3][32])
    __shared__ float  xs[ROWS_PER_BLOCK * 48];   // 12 KiB
    __shared__ float4 tbl[96];                   // (w0,w1,w2,bias) per (c,col)
    __shared__ int    nn[96];                    // node index per (c,col)

    const int tid = threadIdx.x;
    const long long rowbase = (long long)blockIdx.x * ROWS_PER_BLOCK;

    // ---- stage x: 64 rows * 48 floats = 768 float4, coalesced ----
    const float4* xg  = (const float4*)(x + rowbase * 48);
    float4*       xsv = (float4*)xs;
#pragma unroll
    for (int j = 0; j < 3; ++j)
        xsv[tid + j * THREADS] = xg[tid + j * THREADS];

    // ---- build per-(c,col) weight table (tiny; W/b are L2/L3-resident) ----
    if (tid < 96) {
        const int c   = tid >> 5;
        const int col = tid & 31;
        const int s   = c_SRC[col];
        const int n   = s >> 1;
        const int o   = c * 2 + (s & 1);
        const float* wp = W + (n * 6 + o) * 3;   // W[n][o][0..2]
        tbl[tid] = make_float4(wp[0], wp[1], wp[2], bia[n * 6 + o]);
        nn[tid]  = n;
    }
    __syncthreads();

    // ---- compute + coalesced float4 stores: 1536 float4 per block ----
    float4* og = (float4*)(out + rowbase * 96);
#pragma unroll
    for (int j = 0; j < 6; ++j) {
        const int p    = tid + j * THREADS;      // 0..1535
        const int row  = p / 24;                 // 24 float4 per out row
        const int foff = (p - row * 24) * 4;     // float offset in row [0,96)
        const float* xr = xs + row * 48;
        float4 o4;
        float* o4p = (float*)&o4;
#pragma unroll
        for (int q = 0; q < 4; ++q) {
            const int e = foff + q;              // == c*32 + col
            const int n = nn[e];
            const float4 w = tbl[e];
            o4p[q] = xr[n] * w.x + xr[16 + n] * w.y + xr[32 + n] * w.z + w.w;
        }
        og[p] = o4;
    }
}

extern "C" void kernel_launch(void* const* d_in, const int* in_sizes, int n_in,
                              void* d_out, int out_size, void* d_ws, size_t ws_size,
                              hipStream_t stream) {
    const float* x = (const float*)d_in[0];
    const float* W = (const float*)d_in[1];
    const float* b = (const float*)d_in[2];
    float* out = (float*)d_out;

    const int blocks = BF_TOTAL / ROWS_PER_BLOCK;  // 8192
    GraphUpSample_12120397709982_kernel<<<blocks, THREADS, 0, stream>>>(x, W, b, out);
}